// Round 3
// baseline (334.133 us; speedup 1.0000x reference)
//
#include <hip/hip_runtime.h>

#define TAU 1e-3f

typedef __attribute__((ext_vector_type(8))) short bf16x8;
typedef __attribute__((ext_vector_type(4))) float f32x4;

// ws layout: Whi[131072 u16] | Wlo[131072 u16] | accum[512 f32] | counter[u32]
#define ACCUM_OFF (131072 * 2 * 2)  // bytes

// ---- kernel 0: split W fp32 -> bf16 hi/lo; zero accum + counter ----------
__global__ __launch_bounds__(256) void wconv(const float* __restrict__ W,
                                             unsigned short* __restrict__ Whi,
                                             unsigned short* __restrict__ Wlo,
                                             float* __restrict__ accum) {
  int i = (blockIdx.x * 256 + threadIdx.x) * 4;  // 128*256*4 = 131072 exact
  float4 f = *(const float4*)(W + i);
  float fv[4] = {f.x, f.y, f.z, f.w};
  unsigned short h[4], l[4];
#pragma unroll
  for (int j = 0; j < 4; ++j) {
    unsigned u = __float_as_uint(fv[j]);
    h[j] = (unsigned short)(u >> 16);
    float r = fv[j] - __uint_as_float(u & 0xffff0000u);
    l[j] = (unsigned short)(__float_as_uint(r) >> 16);
  }
  *(ushort4*)(Whi + i) = make_ushort4(h[0], h[1], h[2], h[3]);
  *(ushort4*)(Wlo + i) = make_ushort4(l[0], l[1], l[2], l[3]);
  if (blockIdx.x == 0) {
    accum[threadIdx.x] = 0.f;
    accum[256 + threadIdx.x] = 0.f;
    if (threadIdx.x == 0) ((unsigned*)accum)[512] = 0u;
  }
}

#define CVT(f, j)                                        \
  {                                                      \
    unsigned u_ = __float_as_uint(f);                    \
    ah[j] = (short)(u_ >> 16);                           \
    float r_ = (f)-__uint_as_float(u_ & 0xffff0000u);    \
    al[j] = (short)(__float_as_uint(r_) >> 16);          \
  }

// ---- kernel 1: main gate --------------------------------------------------
// 1024 blocks x 256. Block: 16 tokens, all 64 experts. Wave w: K-quarter
// [w*512, w*512+512). No barriers / no LDS in the K-loop.
__global__ __launch_bounds__(256, 4) void gate_main(
    const float* __restrict__ x, const float* __restrict__ Wf,
    const unsigned short* __restrict__ Whi, const unsigned short* __restrict__ Wlo,
    float* __restrict__ out, float* __restrict__ accum) {
  // pitch 76: epilogue-only traffic, <=2-way banks for reduce reads
  __shared__ float part[4][16][76];
  __shared__ float m2s[16], m1s[16], izs[16];
  __shared__ int i1s[16], i2s[16];

  const int tid = threadIdx.x;
  const int lane = tid & 63;
  const int w = tid >> 6;      // K-quarter
  const int fm = lane & 15;    // A row (token) / B row (expert within group)
  const int kg = lane >> 4;    // k-subgroup (8 elems each)
  const int tok0 = blockIdx.x * 16;

  const float* xp = x + (size_t)(tok0 + fm) * 2048 + w * 512 + kg * 8;
  const unsigned short* whp = Whi + fm * 2048 + w * 512 + kg * 8;
  const unsigned short* wlp = Wlo + fm * 2048 + w * 512 + kg * 8;

  f32x4 acc0 = {0.f, 0.f, 0.f, 0.f}, acc1 = acc0, acc2 = acc0, acc3 = acc0;

  for (int sc = 0; sc < 4; ++sc) {  // super-chunk k=128
    const float* xq = xp + sc * 128;
    // batch 8 A-loads (2 KB/wave in flight)
    float4 ar[8];
#pragma unroll
    for (int s = 0; s < 4; ++s) {
      ar[2 * s] = *(const float4*)(xq + s * 32);
      ar[2 * s + 1] = *(const float4*)(xq + s * 32 + 4);
    }
#pragma unroll
    for (int s = 0; s < 4; ++s) {
      const int ko = sc * 128 + s * 32;
      // clump all 8 W loads (L2) so one waitcnt covers them; conversion
      // below overlaps their latency (no dependence)
      bf16x8 bh0 = *(const bf16x8*)(whp + ko);
      bf16x8 bl0 = *(const bf16x8*)(wlp + ko);
      bf16x8 bh1 = *(const bf16x8*)(whp + 32768 + ko);
      bf16x8 bl1 = *(const bf16x8*)(wlp + 32768 + ko);
      bf16x8 bh2 = *(const bf16x8*)(whp + 65536 + ko);
      bf16x8 bl2 = *(const bf16x8*)(wlp + 65536 + ko);
      bf16x8 bh3 = *(const bf16x8*)(whp + 98304 + ko);
      bf16x8 bl3 = *(const bf16x8*)(wlp + 98304 + ko);
      float4 a0 = ar[2 * s], a1 = ar[2 * s + 1];
      bf16x8 ah, al;
      CVT(a0.x, 0) CVT(a0.y, 1) CVT(a0.z, 2) CVT(a0.w, 3)
      CVT(a1.x, 4) CVT(a1.y, 5) CVT(a1.z, 6) CVT(a1.w, 7)
      acc0 = __builtin_amdgcn_mfma_f32_16x16x32_bf16(ah, bh0, acc0, 0, 0, 0);
      acc1 = __builtin_amdgcn_mfma_f32_16x16x32_bf16(ah, bh1, acc1, 0, 0, 0);
      acc2 = __builtin_amdgcn_mfma_f32_16x16x32_bf16(ah, bh2, acc2, 0, 0, 0);
      acc3 = __builtin_amdgcn_mfma_f32_16x16x32_bf16(ah, bh3, acc3, 0, 0, 0);
      acc0 = __builtin_amdgcn_mfma_f32_16x16x32_bf16(ah, bl0, acc0, 0, 0, 0);
      acc1 = __builtin_amdgcn_mfma_f32_16x16x32_bf16(ah, bl1, acc1, 0, 0, 0);
      acc2 = __builtin_amdgcn_mfma_f32_16x16x32_bf16(ah, bl2, acc2, 0, 0, 0);
      acc3 = __builtin_amdgcn_mfma_f32_16x16x32_bf16(ah, bl3, acc3, 0, 0, 0);
      acc0 = __builtin_amdgcn_mfma_f32_16x16x32_bf16(al, bh0, acc0, 0, 0, 0);
      acc1 = __builtin_amdgcn_mfma_f32_16x16x32_bf16(al, bh1, acc1, 0, 0, 0);
      acc2 = __builtin_amdgcn_mfma_f32_16x16x32_bf16(al, bh2, acc2, 0, 0, 0);
      acc3 = __builtin_amdgcn_mfma_f32_16x16x32_bf16(al, bh3, acc3, 0, 0, 0);
    }
  }

  // partials: token = kg*4+r, expert = g*16+fm
#pragma unroll
  for (int r = 0; r < 4; ++r) {
    part[w][kg * 4 + r][0 * 16 + fm] = acc0[r];
    part[w][kg * 4 + r][1 * 16 + fm] = acc1[r];
    part[w][kg * 4 + r][2 * 16 + fm] = acc2[r];
    part[w][kg * 4 + r][3 * 16 + fm] = acc3[r];
  }
  __syncthreads();
  // reduce K-quarters: 1024 (t,e) pairs over 256 threads
#pragma unroll
  for (int p = tid; p < 1024; p += 256) {
    int t = p >> 6, e = p & 63;
    part[0][t][e] = part[0][t][e] + part[1][t][e] + part[2][t][e] + part[3][t][e];
  }
  __syncthreads();

  if (w != 0) return;  // wave 0 epilogue; no further barriers

  const int t = lane;
  float m1 = -3e38f, m2 = -3e38f, m3 = -3e38f;
  int i1 = 0, i2 = 0;
  if (lane < 16) {
    for (int e = 0; e < 64; ++e) {
      float v = part[0][t][e];
      if (v > m1) { m3 = m2; m2 = m1; i2 = i1; m1 = v; i1 = e; }
      else if (v > m2) { m3 = m2; m2 = v; i2 = e; }
      else if (v > m3) { m3 = v; }
    }
    m2s[t] = m2;
  }
  bool flg = (lane < 16) && ((m1 - m2 < TAU) || (m2 - m3 < TAU));
  unsigned long long msk = __ballot(flg);

  // exact fp32 re-dot for near-tie tokens (candidate experts only)
  while (msk) {
    int tt = __ffsll(msk) - 1;
    msk &= msk - 1;
    float thr = m2s[tt] - TAU;
    if (part[0][tt][lane] >= thr) {
      const float* xr = x + (size_t)(tok0 + tt) * 2048;
      const float* wr = Wf + (size_t)lane * 2048;
      float s0 = 0.f, s1 = 0.f, s2 = 0.f, s3 = 0.f;
      for (int k = 0; k < 2048; k += 8) {
        float4 b0 = *(const float4*)(xr + k);
        float4 c0 = *(const float4*)(wr + k);
        float4 b1 = *(const float4*)(xr + k + 4);
        float4 c1 = *(const float4*)(wr + k + 4);
        s0 += b0.x * c0.x + b0.y * c0.y;
        s1 += b0.z * c0.z + b0.w * c0.w;
        s2 += b1.x * c1.x + b1.y * c1.y;
        s3 += b1.z * c1.z + b1.w * c1.w;
      }
      part[0][tt][lane] = (s0 + s1) + (s2 + s3);
    }
  }

  if (lane < 16) {
    m1 = -3e38f; m2 = -3e38f; i1 = 0; i2 = 0;
    for (int e = 0; e < 64; ++e) {
      float v = part[0][t][e];
      if (v > m1) { m2 = m1; i2 = i1; m1 = v; i1 = e; }
      else if (v > m2) { m2 = v; i2 = e; }
    }
    float Z = 0.f;
    for (int e = 0; e < 64; ++e) Z += __expf(part[0][t][e] - m1);
    float iz = 1.f / Z;
    float p1 = iz;
    float p2 = __expf(m2 - m1) * iz;
    float dn = 1.f / (p1 + p2 + 1e-20f);
    size_t tg = (size_t)(tok0 + t);
    out[tg * 2 + 0] = (float)i1;
    out[tg * 2 + 1] = (float)i2;
    out[32768 + tg * 2 + 0] = p1 * dn;
    out[32768 + tg * 2 + 1] = p2 * dn;
    m1s[t] = m1; izs[t] = iz; i1s[t] = i1; i2s[t] = i2;
  }

  // per-(batch,expert) softmax sums + top2 counts
  const int b = blockIdx.x >> 8;
  float ssum = 0.f;
  int cnt = 0;
#pragma unroll
  for (int t2 = 0; t2 < 16; ++t2) {
    ssum += __expf(part[0][t2][lane] - m1s[t2]) * izs[t2];
    cnt += (i1s[t2] == lane) + (i2s[t2] == lane);
  }
  atomicAdd(&accum[b * 64 + lane], ssum);
  atomicAdd(&accum[256 + b * 64 + lane], (float)cnt);

  // last block finalizes aux loss (replaces gate_fin kernel)
  __threadfence();
  unsigned old = 0;
  if (lane == 0) old = atomicAdd((unsigned*)accum + 512, 1u);
  old = (unsigned)__shfl((int)old, 0, 64);
  if (old == 1023u) {
    __threadfence();
    float tot = 0.f;
#pragma unroll
    for (int bb = 0; bb < 4; ++bb) {
      float ss = atomicAdd(&accum[bb * 64 + lane], 0.f);       // coherent read
      float cc = atomicAdd(&accum[256 + bb * 64 + lane], 0.f);
      tot += cc * (1.f / 128.f) * (ss * (1.f / 4096.f));
    }
    for (int o = 32; o; o >>= 1) tot += __shfl_xor(tot, o, 64);
    if (lane == 0) out[65536] = 0.025f * tot;  // alpha/B = 0.1/4
  }
}

extern "C" void kernel_launch(void* const* d_in, const int* in_sizes, int n_in,
                              void* d_out, int out_size, void* d_ws, size_t ws_size,
                              hipStream_t stream) {
  const float* x = (const float*)d_in[0];
  const float* Wf = (const float*)d_in[1];
  float* out = (float*)d_out;
  unsigned short* Whi = (unsigned short*)d_ws;
  unsigned short* Wlo = Whi + 131072;
  float* accum = (float*)((char*)d_ws + ACCUM_OFF);
  wconv<<<128, 256, 0, stream>>>(Wf, Whi, Wlo, accum);
  gate_main<<<1024, 256, 0, stream>>>(x, Wf, Whi, Wlo, out, accum);
}

// Round 4
// 268.926 us; speedup vs baseline: 1.2425x; 1.2425x over previous
//
#include <hip/hip_runtime.h>

#define TAU 2e-4f

typedef __attribute__((ext_vector_type(8))) short bf16x8;
typedef __attribute__((ext_vector_type(4))) float f32x4;

// ws layout: Whi[131072 u16] | Wlo[131072 u16] | accum[512 f32] | counter[u32]
#define ACCUM_OFF (131072 * 2 * 2)  // bytes

// ---- kernel 0: split W fp32 -> bf16 hi/lo; zero accum + counter ----------
__global__ __launch_bounds__(256) void wconv(const float* __restrict__ W,
                                             unsigned short* __restrict__ Whi,
                                             unsigned short* __restrict__ Wlo,
                                             float* __restrict__ accum) {
  int i = (blockIdx.x * 256 + threadIdx.x) * 4;  // 128*256*4 = 131072 exact
  float4 f = *(const float4*)(W + i);
  float fv[4] = {f.x, f.y, f.z, f.w};
  unsigned short h[4], l[4];
#pragma unroll
  for (int j = 0; j < 4; ++j) {
    unsigned u = __float_as_uint(fv[j]);
    h[j] = (unsigned short)(u >> 16);
    float r = fv[j] - __uint_as_float(u & 0xffff0000u);
    l[j] = (unsigned short)(__float_as_uint(r) >> 16);
  }
  *(ushort4*)(Whi + i) = make_ushort4(h[0], h[1], h[2], h[3]);
  *(ushort4*)(Wlo + i) = make_ushort4(l[0], l[1], l[2], l[3]);
  if (blockIdx.x == 0) {
    accum[threadIdx.x] = 0.f;
    accum[256 + threadIdx.x] = 0.f;
    if (threadIdx.x == 0) ((unsigned*)accum)[512] = 0u;
  }
}

#define CVT(f, j)                                        \
  {                                                      \
    unsigned u_ = __float_as_uint(f);                    \
    ah[j] = (short)(u_ >> 16);                           \
    float r_ = (f)-__uint_as_float(u_ & 0xffff0000u);    \
    al[j] = (short)(__float_as_uint(r_) >> 16);          \
  }

#define LDW(it, buf)                                \
  {                                                 \
    const int ko_ = (it) * 32;                      \
    buf[0] = *(const bf16x8*)(whp + ko_);           \
    buf[1] = *(const bf16x8*)(wlp + ko_);           \
    buf[2] = *(const bf16x8*)(whp + 32768 + ko_);   \
    buf[3] = *(const bf16x8*)(wlp + 32768 + ko_);   \
    buf[4] = *(const bf16x8*)(whp + 65536 + ko_);   \
    buf[5] = *(const bf16x8*)(wlp + 65536 + ko_);   \
    buf[6] = *(const bf16x8*)(whp + 98304 + ko_);   \
    buf[7] = *(const bf16x8*)(wlp + 98304 + ko_);   \
  }
#define LDA(it, dst)                                \
  {                                                 \
    const float* p_ = xp + (it) * 32;               \
    dst[0] = *(const float4*)p_;                    \
    dst[1] = *(const float4*)(p_ + 4);              \
  }

// ---- kernel 1: main gate --------------------------------------------------
// 1024 blocks x 256. Block: 16 tokens, all 64 experts. Wave w: K-quarter.
// No barriers/LDS in K-loop; explicit 1-deep register double buffer.
__global__ __launch_bounds__(256, 4) void gate_main(
    const float* __restrict__ x, const float* __restrict__ Wf,
    const unsigned short* __restrict__ Whi, const unsigned short* __restrict__ Wlo,
    float* __restrict__ out, float* __restrict__ accum) {
  __shared__ float part[4][16][76];
  __shared__ float m2s[16], m1s[16], izs[16];
  __shared__ int i1s[16], i2s[16];

  const int tid = threadIdx.x;
  const int lane = tid & 63;
  const int w = tid >> 6;      // K-quarter
  const int fm = lane & 15;    // A row (token) / B row (expert in group)
  const int kg = lane >> 4;    // k-subgroup
  const int tok0 = blockIdx.x * 16;

  const float* xp = x + (size_t)(tok0 + fm) * 2048 + w * 512 + kg * 8;
  const unsigned short* whp = Whi + fm * 2048 + w * 512 + kg * 8;
  const unsigned short* wlp = Wlo + fm * 2048 + w * 512 + kg * 8;

  f32x4 acc0 = {0.f, 0.f, 0.f, 0.f}, acc1 = acc0, acc2 = acc0, acc3 = acc0;

  bf16x8 wb[2][8];
  float4 ab[2][2];
  LDA(0, ab[0]);
  LDW(0, wb[0]);
#pragma unroll
  for (int it = 0; it < 16; ++it) {
    const int cur = it & 1, nxt = cur ^ 1;
    if (it < 15) {
      LDA(it + 1, ab[nxt]);
      LDW(it + 1, wb[nxt]);
    }
    float4 a0 = ab[cur][0], a1 = ab[cur][1];
    bf16x8 ah, al;
    CVT(a0.x, 0) CVT(a0.y, 1) CVT(a0.z, 2) CVT(a0.w, 3)
    CVT(a1.x, 4) CVT(a1.y, 5) CVT(a1.z, 6) CVT(a1.w, 7)
    acc0 = __builtin_amdgcn_mfma_f32_16x16x32_bf16(ah, wb[cur][0], acc0, 0, 0, 0);
    acc1 = __builtin_amdgcn_mfma_f32_16x16x32_bf16(ah, wb[cur][2], acc1, 0, 0, 0);
    acc2 = __builtin_amdgcn_mfma_f32_16x16x32_bf16(ah, wb[cur][4], acc2, 0, 0, 0);
    acc3 = __builtin_amdgcn_mfma_f32_16x16x32_bf16(ah, wb[cur][6], acc3, 0, 0, 0);
    acc0 = __builtin_amdgcn_mfma_f32_16x16x32_bf16(ah, wb[cur][1], acc0, 0, 0, 0);
    acc1 = __builtin_amdgcn_mfma_f32_16x16x32_bf16(ah, wb[cur][3], acc1, 0, 0, 0);
    acc2 = __builtin_amdgcn_mfma_f32_16x16x32_bf16(ah, wb[cur][5], acc2, 0, 0, 0);
    acc3 = __builtin_amdgcn_mfma_f32_16x16x32_bf16(ah, wb[cur][7], acc3, 0, 0, 0);
    acc0 = __builtin_amdgcn_mfma_f32_16x16x32_bf16(al, wb[cur][0], acc0, 0, 0, 0);
    acc1 = __builtin_amdgcn_mfma_f32_16x16x32_bf16(al, wb[cur][2], acc1, 0, 0, 0);
    acc2 = __builtin_amdgcn_mfma_f32_16x16x32_bf16(al, wb[cur][4], acc2, 0, 0, 0);
    acc3 = __builtin_amdgcn_mfma_f32_16x16x32_bf16(al, wb[cur][6], acc3, 0, 0, 0);
  }

  // partials: token = kg*4+r, expert = g*16+fm
#pragma unroll
  for (int r = 0; r < 4; ++r) {
    part[w][kg * 4 + r][0 * 16 + fm] = acc0[r];
    part[w][kg * 4 + r][1 * 16 + fm] = acc1[r];
    part[w][kg * 4 + r][2 * 16 + fm] = acc2[r];
    part[w][kg * 4 + r][3 * 16 + fm] = acc3[r];
  }
  __syncthreads();
#pragma unroll
  for (int p = tid; p < 1024; p += 256) {
    int t = p >> 6, e = p & 63;
    part[0][t][e] = part[0][t][e] + part[1][t][e] + part[2][t][e] + part[3][t][e];
  }
  __syncthreads();

  if (w != 0) return;  // wave 0 epilogue; no further barriers

  const int t = lane;
  float m1 = -3e38f, m2 = -3e38f, m3 = -3e38f;
  int i1 = 0, i2 = 0;
  if (lane < 16) {
    for (int e = 0; e < 64; ++e) {
      float v = part[0][t][e];
      if (v > m1) { m3 = m2; m2 = m1; i2 = i1; m1 = v; i1 = e; }
      else if (v > m2) { m3 = m2; m2 = v; i2 = e; }
      else if (v > m3) { m3 = v; }
    }
    m2s[t] = m2;
  }
  bool flg = (lane < 16) && ((m1 - m2 < TAU) || (m2 - m3 < TAU));
  unsigned long long msk = __ballot(flg);

  // exact fp32 re-dot for near-tie tokens: wave-cooperative (k split over
  // 64 lanes, coalesced), one candidate expert at a time
  while (msk) {
    int tt = __ffsll(msk) - 1;
    msk &= msk - 1;
    float thr = m2s[tt] - TAU;
    unsigned long long cand = __ballot(part[0][tt][lane] >= thr);
    const float* xr = x + (size_t)(tok0 + tt) * 2048 + lane * 32;
    while (cand) {
      int e = __ffsll(cand) - 1;
      cand &= cand - 1;
      const float* wr = Wf + (size_t)e * 2048 + lane * 32;
      float s = 0.f;
#pragma unroll
      for (int kk = 0; kk < 32; kk += 8) {
        float4 b0 = *(const float4*)(xr + kk);
        float4 c0 = *(const float4*)(wr + kk);
        float4 b1 = *(const float4*)(xr + kk + 4);
        float4 c1 = *(const float4*)(wr + kk + 4);
        s += b0.x * c0.x + b0.y * c0.y + b0.z * c0.z + b0.w * c0.w +
             b1.x * c1.x + b1.y * c1.y + b1.z * c1.z + b1.w * c1.w;
      }
      for (int o = 32; o; o >>= 1) s += __shfl_xor(s, o, 64);
      if (lane == 0) part[0][tt][e] = s;
    }
  }

  if (lane < 16) {
    m1 = -3e38f; m2 = -3e38f; i1 = 0; i2 = 0;
    for (int e = 0; e < 64; ++e) {
      float v = part[0][t][e];
      if (v > m1) { m2 = m1; i2 = i1; m1 = v; i1 = e; }
      else if (v > m2) { m2 = v; i2 = e; }
    }
    float Z = 0.f;
    for (int e = 0; e < 64; ++e) Z += __expf(part[0][t][e] - m1);
    float iz = 1.f / Z;
    float p1 = iz;
    float p2 = __expf(m2 - m1) * iz;
    float dn = 1.f / (p1 + p2 + 1e-20f);
    size_t tg = (size_t)(tok0 + t);
    out[tg * 2 + 0] = (float)i1;
    out[tg * 2 + 1] = (float)i2;
    out[32768 + tg * 2 + 0] = p1 * dn;
    out[32768 + tg * 2 + 1] = p2 * dn;
    m1s[t] = m1; izs[t] = iz; i1s[t] = i1; i2s[t] = i2;
  }

  // per-(batch,expert) softmax sums + top2 counts
  const int b = blockIdx.x >> 8;
  float ssum = 0.f;
  int cnt = 0;
#pragma unroll
  for (int t2 = 0; t2 < 16; ++t2) {
    ssum += __expf(part[0][t2][lane] - m1s[t2]) * izs[t2];
    cnt += (i1s[t2] == lane) + (i2s[t2] == lane);
  }
  atomicAdd(&accum[b * 64 + lane], ssum);
  atomicAdd(&accum[256 + b * 64 + lane], (float)cnt);

  // last block finalizes aux loss
  __threadfence();
  unsigned old = 0;
  if (lane == 0) old = atomicAdd((unsigned*)accum + 512, 1u);
  old = (unsigned)__shfl((int)old, 0, 64);
  if (old == 1023u) {
    __threadfence();
    float tot = 0.f;
#pragma unroll
    for (int bb = 0; bb < 4; ++bb) {
      float ss = atomicAdd(&accum[bb * 64 + lane], 0.f);
      float cc = atomicAdd(&accum[256 + bb * 64 + lane], 0.f);
      tot += cc * (1.f / 128.f) * (ss * (1.f / 4096.f));
    }
    for (int o = 32; o; o >>= 1) tot += __shfl_xor(tot, o, 64);
    if (lane == 0) out[65536] = 0.025f * tot;  // alpha/B = 0.1/4
  }
}

extern "C" void kernel_launch(void* const* d_in, const int* in_sizes, int n_in,
                              void* d_out, int out_size, void* d_ws, size_t ws_size,
                              hipStream_t stream) {
  const float* x = (const float*)d_in[0];
  const float* Wf = (const float*)d_in[1];
  float* out = (float*)d_out;
  unsigned short* Whi = (unsigned short*)d_ws;
  unsigned short* Wlo = Whi + 131072;
  float* accum = (float*)((char*)d_ws + ACCUM_OFF);
  wconv<<<128, 256, 0, stream>>>(Wf, Whi, Wlo, accum);
  gate_main<<<1024, 256, 0, stream>>>(x, Wf, Whi, Wlo, out, accum);
}

// Round 5
// 223.624 us; speedup vs baseline: 1.4942x; 1.2026x over previous
//
#include <hip/hip_runtime.h>

#define TAU 8e-3f

typedef __attribute__((ext_vector_type(8))) short bf16x8;
typedef __attribute__((ext_vector_type(4))) float f32x4;

// ws layout: Wswz[4*64*64*8 u16 = 256 KB] | accum[512 f32] | counter[u32]
#define ACCUM_OFF 262144

// round-to-nearest-even fp32 -> bf16 (as u16)
#define RNE16(f) \
  ((unsigned short)((__float_as_uint(f) + 0x7fffu + ((__float_as_uint(f) >> 16) & 1u)) >> 16))

// ---- kernel 0: W fp32 -> bf16, swizzled to MFMA-fragment-linear ----------
// Wswz[g][ks][lane] (8 u16 each): lane(fm,kg) holds W[g*16+fm][ks*32+kg*8 .. +8]
__global__ __launch_bounds__(256) void wconv(const float* __restrict__ W,
                                             unsigned short* __restrict__ Wswz,
                                             float* __restrict__ accum) {
  int t = blockIdx.x * 256 + threadIdx.x;  // 64 blocks -> 16384 threads
  int g = t >> 12, rem = t & 4095;
  int ks = rem >> 6, lane = rem & 63;
  int fm = lane & 15, kg = lane >> 4;
  const float* src = W + (size_t)(g * 16 + fm) * 2048 + ks * 32 + kg * 8;
  float4 a = *(const float4*)src;
  float4 b = *(const float4*)(src + 4);
  ushort4 lo = make_ushort4(RNE16(a.x), RNE16(a.y), RNE16(a.z), RNE16(a.w));
  ushort4 hi = make_ushort4(RNE16(b.x), RNE16(b.y), RNE16(b.z), RNE16(b.w));
  unsigned short* dst = Wswz + (size_t)t * 8;
  *(ushort4*)dst = lo;
  *(ushort4*)(dst + 4) = hi;
  if (blockIdx.x == 0) {
    accum[threadIdx.x] = 0.f;
    accum[256 + threadIdx.x] = 0.f;
    if (threadIdx.x == 0) ((unsigned*)accum)[512] = 0u;
  }
}

#define CVT8(d, p0, p1)              \
  {                                  \
    d[0] = (short)RNE16(p0.x);       \
    d[1] = (short)RNE16(p0.y);       \
    d[2] = (short)RNE16(p0.z);       \
    d[3] = (short)RNE16(p0.w);       \
    d[4] = (short)RNE16(p1.x);       \
    d[5] = (short)RNE16(p1.y);       \
    d[6] = (short)RNE16(p1.z);       \
    d[7] = (short)RNE16(p1.w);       \
  }

// ---- kernel 1: main gate --------------------------------------------------
// 512 blocks x 512 threads (8 waves). Block: 32 tokens, all 64 experts.
// Wave w: K-eighth [w*256, w*256+256). No barriers/LDS in the K-loop.
__global__ __launch_bounds__(512, 4) void gate_main(
    const float* __restrict__ x, const float* __restrict__ Wf,
    const unsigned short* __restrict__ Wswz,
    float* __restrict__ out, float* __restrict__ accum) {
  __shared__ float part[8][32][68];  // pitch 68: <=2-way banks
  __shared__ float m2s[32], m1s[32], izs[32];
  __shared__ int i1s[32], i2s[32];

  const int tid = threadIdx.x;
  const int lane = tid & 63;
  const int w = __builtin_amdgcn_readfirstlane(tid >> 6);  // K-eighth 0..7
  const int fm = lane & 15;
  const int kg = lane >> 4;
  const int tok0 = blockIdx.x * 32;

  const float* xr0 = x + (size_t)(tok0 + fm) * 2048 + w * 256 + kg * 8;
  const float* xr1 = xr0 + (size_t)16 * 2048;
  const bf16x8* wsw = (const bf16x8*)Wswz + lane;  // + (g*64+ks)*64

  f32x4 acc[2][4];
#pragma unroll
  for (int f = 0; f < 2; ++f)
#pragma unroll
    for (int g = 0; g < 4; ++g) acc[f][g] = (f32x4){0.f, 0.f, 0.f, 0.f};

#pragma unroll
  for (int it = 0; it < 8; ++it) {
    const int ks = w * 8 + it;
    float4 p0 = *(const float4*)(xr0 + it * 32);
    float4 p1 = *(const float4*)(xr0 + it * 32 + 4);
    float4 q0 = *(const float4*)(xr1 + it * 32);
    float4 q1 = *(const float4*)(xr1 + it * 32 + 4);
    bf16x8 b0 = wsw[(0 * 64 + ks) * 64];
    bf16x8 b1 = wsw[(1 * 64 + ks) * 64];
    bf16x8 b2 = wsw[(2 * 64 + ks) * 64];
    bf16x8 b3 = wsw[(3 * 64 + ks) * 64];
    bf16x8 a0, a1;
    CVT8(a0, p0, p1)
    CVT8(a1, q0, q1)
    acc[0][0] = __builtin_amdgcn_mfma_f32_16x16x32_bf16(a0, b0, acc[0][0], 0, 0, 0);
    acc[0][1] = __builtin_amdgcn_mfma_f32_16x16x32_bf16(a0, b1, acc[0][1], 0, 0, 0);
    acc[0][2] = __builtin_amdgcn_mfma_f32_16x16x32_bf16(a0, b2, acc[0][2], 0, 0, 0);
    acc[0][3] = __builtin_amdgcn_mfma_f32_16x16x32_bf16(a0, b3, acc[0][3], 0, 0, 0);
    acc[1][0] = __builtin_amdgcn_mfma_f32_16x16x32_bf16(a1, b0, acc[1][0], 0, 0, 0);
    acc[1][1] = __builtin_amdgcn_mfma_f32_16x16x32_bf16(a1, b1, acc[1][1], 0, 0, 0);
    acc[1][2] = __builtin_amdgcn_mfma_f32_16x16x32_bf16(a1, b2, acc[1][2], 0, 0, 0);
    acc[1][3] = __builtin_amdgcn_mfma_f32_16x16x32_bf16(a1, b3, acc[1][3], 0, 0, 0);
  }

  // C-layout: token = f*16 + kg*4 + r, expert = g*16 + fm
#pragma unroll
  for (int f = 0; f < 2; ++f)
#pragma unroll
    for (int g = 0; g < 4; ++g)
#pragma unroll
      for (int r = 0; r < 4; ++r)
        part[w][f * 16 + kg * 4 + r][g * 16 + fm] = acc[f][g][r];
  __syncthreads();

  // reduce 8 K-eighths: 2048 cells over 512 threads
#pragma unroll
  for (int p = tid; p < 2048; p += 512) {
    int t = p >> 6, e = p & 63;
    float s = part[0][t][e];
#pragma unroll
    for (int ww = 1; ww < 8; ++ww) s += part[ww][t][e];
    part[0][t][e] = s;
  }
  __syncthreads();

  if (w != 0) return;  // wave 0 epilogue; no further barriers

  const int t = lane;
  float m1 = -3e38f, m2 = -3e38f, m3 = -3e38f;
  int i1 = 0, i2 = 0;
  if (lane < 32) {
    for (int e = 0; e < 64; ++e) {
      float v = part[0][t][e];
      if (v > m1) { m3 = m2; m2 = m1; i2 = i1; m1 = v; i1 = e; }
      else if (v > m2) { m3 = m2; m2 = v; i2 = e; }
      else if (v > m3) { m3 = v; }
    }
    m2s[t] = m2;
  }
  bool flg = (lane < 32) && ((m1 - m2 < TAU) || (m2 - m3 < TAU));
  unsigned long long msk = __ballot(flg);

  // exact fp32 re-dot for near-tie tokens: whole wave, k split over lanes
  while (msk) {
    int tt = __ffsll(msk) - 1;
    msk &= msk - 1;
    float thr = m2s[tt] - TAU;
    unsigned long long cand = __ballot(part[0][tt][lane] >= thr);
    const float* xr = x + (size_t)(tok0 + tt) * 2048 + lane * 32;
    while (cand) {
      int e = __ffsll(cand) - 1;
      cand &= cand - 1;
      const float* wr = Wf + (size_t)e * 2048 + lane * 32;
      float s = 0.f;
#pragma unroll
      for (int kk = 0; kk < 32; kk += 8) {
        float4 u0 = *(const float4*)(xr + kk);
        float4 v0 = *(const float4*)(wr + kk);
        float4 u1 = *(const float4*)(xr + kk + 4);
        float4 v1 = *(const float4*)(wr + kk + 4);
        s += u0.x * v0.x + u0.y * v0.y + u0.z * v0.z + u0.w * v0.w +
             u1.x * v1.x + u1.y * v1.y + u1.z * v1.z + u1.w * v1.w;
      }
      for (int o = 32; o; o >>= 1) s += __shfl_xor(s, o, 64);
      if (lane == 0) part[0][tt][e] = s;
    }
  }

  if (lane < 32) {
    m1 = -3e38f; m2 = -3e38f; i1 = 0; i2 = 0;
    for (int e = 0; e < 64; ++e) {
      float v = part[0][t][e];
      if (v > m1) { m2 = m1; i2 = i1; m1 = v; i1 = e; }
      else if (v > m2) { m2 = v; i2 = e; }
    }
    float Z = 0.f;
    for (int e = 0; e < 64; ++e) Z += __expf(part[0][t][e] - m1);
    float iz = 1.f / Z;
    float p1 = iz;
    float p2 = __expf(m2 - m1) * iz;
    float dn = 1.f / (p1 + p2 + 1e-20f);
    size_t tg = (size_t)(tok0 + t);
    out[tg * 2 + 0] = (float)i1;
    out[tg * 2 + 1] = (float)i2;
    out[32768 + tg * 2 + 0] = p1 * dn;
    out[32768 + tg * 2 + 1] = p2 * dn;
    m1s[t] = m1; izs[t] = iz; i1s[t] = i1; i2s[t] = i2;
  }

  // per-(batch,expert) softmax sums + top2 counts (lane = expert)
  const int b = blockIdx.x >> 7;  // 128 blocks per batch row
  float ssum = 0.f;
  int cnt = 0;
#pragma unroll
  for (int t2 = 0; t2 < 32; ++t2) {
    ssum += __expf(part[0][t2][lane] - m1s[t2]) * izs[t2];
    cnt += (i1s[t2] == lane) + (i2s[t2] == lane);
  }
  atomicAdd(&accum[b * 64 + lane], ssum);
  atomicAdd(&accum[256 + b * 64 + lane], (float)cnt);

  // last block finalizes aux loss
  __threadfence();
  unsigned old = 0;
  if (lane == 0) old = atomicAdd((unsigned*)accum + 512, 1u);
  old = (unsigned)__shfl((int)old, 0, 64);
  if (old == 511u) {
    __threadfence();
    float tot = 0.f;
#pragma unroll
    for (int bb = 0; bb < 4; ++bb) {
      float ss = atomicAdd(&accum[bb * 64 + lane], 0.f);
      float cc = atomicAdd(&accum[256 + bb * 64 + lane], 0.f);
      tot += cc * (1.f / 128.f) * (ss * (1.f / 4096.f));
    }
    for (int o = 32; o; o >>= 1) tot += __shfl_xor(tot, o, 64);
    if (lane == 0) out[65536] = 0.025f * tot;  // alpha/B = 0.1/4
  }
}

extern "C" void kernel_launch(void* const* d_in, const int* in_sizes, int n_in,
                              void* d_out, int out_size, void* d_ws, size_t ws_size,
                              hipStream_t stream) {
  const float* x = (const float*)d_in[0];
  const float* Wf = (const float*)d_in[1];
  float* out = (float*)d_out;
  unsigned short* Wswz = (unsigned short*)d_ws;
  float* accum = (float*)((char*)d_ws + ACCUM_OFF);
  wconv<<<64, 256, 0, stream>>>(Wf, Wswz, accum);
  gate_main<<<512, 512, 0, stream>>>(x, Wf, Wswz, out, accum);
}